// Round 11
// baseline (434.709 us; speedup 1.0000x reference)
//
#include <hip/hip_runtime.h>
#include <hip/hip_bf16.h>
#include <cmath>
#include <cstdint>
#include <cstddef>

#define DEV __device__ __forceinline__

typedef __attribute__((ext_vector_type(4))) float f32x4;
typedef __attribute__((ext_vector_type(8))) short bf16x8;
typedef __attribute__((ext_vector_type(4))) unsigned int u32x4;
typedef __attribute__((ext_vector_type(4))) unsigned short u16x4;

constexpr int NBATCH = 32;
constexpr int SEQ    = 197;
constexpr int CH     = 768;
constexpr int H3     = 3 * CH;      // 2304
constexpr int NHEADS = 12;
constexpr int HD     = 64;
constexpr int HID    = 3072;
constexpr int TOK    = NBATCH * SEQ;  // 6304
constexpr int TOKP   = 6400;          // padded to 50*128
constexpr float LNEPS = 1e-5f;

DEV unsigned short f2bf(float f) {
  unsigned int u = __builtin_bit_cast(unsigned int, f);
  u += 0x7fffu + ((u >> 16) & 1u);   // RNE
  return (unsigned short)(u >> 16);
}
DEV float bf2f(unsigned short s) {
  unsigned int u = ((unsigned int)s) << 16;
  return __builtin_bit_cast(float, u);
}

// fast tanh: tanh(x) = 1 - 2/(e^{2x}+1); saturates correctly at +-1
DEV float fast_tanh(float x) {
  const float e = __expf(2.f * x);
  return 1.f - 2.f * __builtin_amdgcn_rcpf(e + 1.f);
}

// async global->LDS, 16B per lane; lds dest is wave-uniform base + lane*16 (linear)
DEV void async_copy16(void* lds, const void* gmem) {
  __builtin_amdgcn_global_load_lds(
      (const __attribute__((address_space(1))) unsigned int*)gmem,
      (__attribute__((address_space(3))) unsigned int*)lds, 16, 0, 0);
}

// ---------------- LayerNorm (one wave per row), optional tanh, bf16 out -------------
template <int DO_TANH>
__global__ void ln_kernel(const float* __restrict__ xin, const float* __restrict__ gg,
                          const float* __restrict__ bb, unsigned short* __restrict__ outp) {
  const int row  = blockIdx.x * 4 + (threadIdx.x >> 6);
  const int lane = threadIdx.x & 63;
  if (row >= TOK) {           // pad rows -> zeros (row < TOKP by grid)
    u16x4 z = {0, 0, 0, 0};
    #pragma unroll
    for (int c = 0; c < 3; ++c)
      *(u16x4*)&outp[(size_t)row * CH + c * 256 + lane * 4] = z;
    return;
  }
  f32x4 v[3];
  float s = 0.f, s2 = 0.f;
  #pragma unroll
  for (int c = 0; c < 3; ++c) {
    v[c] = *(const f32x4*)&xin[(size_t)row * CH + c * 256 + lane * 4];
    #pragma unroll
    for (int e = 0; e < 4; ++e) { s += v[c][e]; s2 += v[c][e] * v[c][e]; }
  }
  #pragma unroll
  for (int off = 32; off; off >>= 1) { s += __shfl_xor(s, off); s2 += __shfl_xor(s2, off); }
  const float mean = s * (1.f / CH);
  const float var  = s2 * (1.f / CH) - mean * mean;
  const float rs   = rsqrtf(var + LNEPS);
  #pragma unroll
  for (int c = 0; c < 3; ++c) {
    f32x4 gv = *(const f32x4*)&gg[c * 256 + lane * 4];
    f32x4 bv = *(const f32x4*)&bb[c * 256 + lane * 4];
    u16x4 o;
    #pragma unroll
    for (int e = 0; e < 4; ++e) {
      float f = (v[c][e] - mean) * rs * gv[e] + bv[e];
      if (DO_TANH) f = fast_tanh(f);
      o[e] = f2bf(f);
    }
    *(u16x4*)&outp[(size_t)row * CH + c * 256 + lane * 4] = o;
  }
}

// ---------------- transpose fp32 (K x N) -> bf16 (N x K) ----------------------------
__global__ void transpose_bf16(const float* __restrict__ in, unsigned short* __restrict__ outp,
                               int K, int N) {
  __shared__ unsigned short tile[64][65];
  const int k0 = blockIdx.x * 64, n0 = blockIdx.y * 64;
  const int tc = threadIdx.x & 63, tr = threadIdx.x >> 6;
  #pragma unroll
  for (int rr = 0; rr < 64; rr += 4)
    tile[rr + tr][tc] = f2bf(in[(size_t)(k0 + rr + tr) * N + n0 + tc]);
  __syncthreads();
  #pragma unroll
  for (int rr = 0; rr < 64; rr += 4)
    outp[(size_t)(n0 + rr + tr) * K + k0 + tc] = tile[tc][rr + tr];
}

// -------- fold cheby coeffs (I,O,4) -> monomial weight planes bf16 [3][O][I] --------
// W1 = c[...,1]-3c[...,3], W2 = 2c[...,2], W3 = 4c[...,3]
// Also emits per-(i-block) partial bias rows: partial[iblk][o] = sum_{i in blk}(c0 - c2)
__global__ void cheb_combine(const float* __restrict__ cc, unsigned short* __restrict__ outp,
                             float* __restrict__ partial, int I, int O) {
  __shared__ unsigned short t1[64][65];
  __shared__ unsigned short t2[64][65];
  __shared__ unsigned short t3[64][65];
  __shared__ float psum[4][64];
  const int i0 = blockIdx.x * 64, o0 = blockIdx.y * 64;
  const int tc = threadIdx.x & 63, tr = threadIdx.x >> 6;
  float bs = 0.f;
  #pragma unroll
  for (int rr = 0; rr < 64; rr += 4) {
    f32x4 v = *(const f32x4*)&cc[((size_t)(i0 + rr + tr) * O + (o0 + tc)) * 4];
    t1[rr + tr][tc] = f2bf(v[1] - 3.f * v[3]);
    t2[rr + tr][tc] = f2bf(2.f * v[2]);
    t3[rr + tr][tc] = f2bf(4.f * v[3]);
    bs += v[0] - v[2];
  }
  psum[tr][tc] = bs;
  __syncthreads();
  const size_t plane = (size_t)O * I;
  #pragma unroll
  for (int rr = 0; rr < 64; rr += 4) {
    size_t ob = (size_t)(o0 + rr + tr) * I + i0 + tc;
    outp[ob]             = t1[tc][rr + tr];
    outp[ob + plane]     = t2[tc][rr + tr];
    outp[ob + 2 * plane] = t3[tc][rr + tr];
  }
  if (tr == 0)
    partial[(size_t)blockIdx.x * O + o0 + tc] =
        psum[0][tc] + psum[1][tc] + psum[2][tc] + psum[3][tc];
}

// deterministic finish: bias[o] = sum_k partial[k][o]
__global__ void bias_finish(const float* __restrict__ partial, float* __restrict__ bias,
                            int nblk, int O) {
  const int o = blockIdx.x * 256 + threadIdx.x;
  float s = 0.f;
  for (int k = 0; k < nblk; ++k) s += partial[(size_t)k * O + o];
  bias[o] = s;
}

__global__ void zero_pad_rows(unsigned short* __restrict__ p) {
  const size_t idx = ((size_t)blockIdx.x * 256 + threadIdx.x) * 4;
  u16x4 z = {0, 0, 0, 0};
  *(u16x4*)&p[(size_t)TOK * CH + idx] = z;
}

// ---------------- 128x128x32 bf16 MFMA GEMM, 1-ahead prefetch (round-6 form) --------
// A bf16 [TOKP][Ktot] row-major; BT bf16 [Nn][Ktot]. 256 thr, 2x2 waves.
// EPI: 0 -> bf16 C[row][Nn] ; 1 -> fp32 acc+bias+resid (0 on pad rows)
template <int EPI>
__global__ __launch_bounds__(256)
void gemm_kernel(const unsigned short* __restrict__ A,
                 const unsigned short* __restrict__ BT,
                 const int Ktot, const int Nn,
                 const float* __restrict__ bias,
                 const float* __restrict__ resid,
                 void* __restrict__ Cout) {
  __shared__ __align__(16) unsigned short As[2][128 * 32];
  __shared__ __align__(16) unsigned short Bs[2][128 * 32];
  const int t = threadIdx.x;
  const int lane = t & 63;
  const int wid = t >> 6;
  const int wm = wid >> 1, wn = wid & 1;
  const int bm = blockIdx.x * 128;
  const int bn = blockIdx.y * 128;
  const int srow = t >> 2;          // staging row within 64-row half
  const int scol = (t & 3) * 8;     // staging col (bf16)
  const int nkt = Ktot >> 5;
  f32x4 acc[4][4] = {};

  auto stage = [&](int buf, int kt) {
    const int kk = kt << 5;
    char* lb = (char*)&Bs[buf][0] + (wid << 10);
    async_copy16(lb,        &BT[(size_t)(bn + srow) * Ktot + kk + scol]);
    async_copy16(lb + 4096, &BT[(size_t)(bn + 64 + srow) * Ktot + kk + scol]);
    char* la = (char*)&As[buf][0] + (wid << 10);
    async_copy16(la,        &A[(size_t)(bm + srow) * Ktot + kk + scol]);
    async_copy16(la + 4096, &A[(size_t)(bm + 64 + srow) * Ktot + kk + scol]);
  };

  int cur = 0;
  stage(0, 0);
  for (int kt = 0; kt < nkt; ++kt) {
    if (kt + 1 < nkt) {
      stage(cur ^ 1, kt + 1);                       // issue next tile's loads first
      asm volatile("s_waitcnt vmcnt(4)" ::: "memory");   // cur tile's 4 loads done
    } else {
      asm volatile("s_waitcnt vmcnt(0)" ::: "memory");
    }
    __builtin_amdgcn_s_barrier();                   // cur staged by all waves
    __builtin_amdgcn_sched_barrier(0);
    bf16x8 af[4], bfr[4];
    const int frow = lane & 15;
    const int fk = (lane >> 4) * 8;
    #pragma unroll
    for (int m = 0; m < 4; ++m)
      af[m] = *(const bf16x8*)&As[cur][(wm * 64 + m * 16 + frow) * 32 + fk];
    #pragma unroll
    for (int n = 0; n < 4; ++n)
      bfr[n] = *(const bf16x8*)&Bs[cur][(wn * 64 + n * 16 + frow) * 32 + fk];
    #pragma unroll
    for (int m = 0; m < 4; ++m)
      #pragma unroll
      for (int n = 0; n < 4; ++n)
        acc[m][n] = __builtin_amdgcn_mfma_f32_16x16x32_bf16(af[m], bfr[n], acc[m][n], 0, 0, 0);
    __builtin_amdgcn_s_barrier();                   // reads done before next overwrite
    cur ^= 1;
  }
  // epilogue: C/D frag layout col=lane&15, row=4*(lane>>4)+r  [verified m89]
  #pragma unroll
  for (int m = 0; m < 4; ++m) {
    #pragma unroll
    for (int n = 0; n < 4; ++n) {
      #pragma unroll
      for (int r = 0; r < 4; ++r) {
        const int row = bm + wm * 64 + m * 16 + (lane >> 4) * 4 + r;
        const int col = bn + wn * 64 + n * 16 + (lane & 15);
        const float v = acc[m][n][r];
        if (EPI == 0) {
          ((unsigned short*)Cout)[(size_t)row * Nn + col] = f2bf(v);
        } else {
          float o = 0.f;
          if (row < TOK) o = v + bias[col] + resid[(size_t)row * Nn + col];
          ((float*)Cout)[(size_t)row * Nn + col] = o;
        }
      }
    }
  }
}

// ---------------- fused ChebyKAN GEMM (round-7 form): 128x64 tile, 4x1 waves --------
// A (t or u) global->reg direct (1-ahead, 2 named reg sets); powers expanded in regs.
// B: 3 power planes [3][Nn][Ktot]; LDS 3-buffer, 2-deep prefetch, ONE barrier/k-tile,
// counted vmcnt(3) (never drains mid-loop). T2 swizzle on Bs. 36 KB LDS, 64 VGPR.
// EPI: 0 -> bf16 fast_tanh(acc+bias) -> C[row][Nn]
//      1 -> fp32 acc+bias+resid -> C[row][Nn], rows<TOK only (direct d_out)
template <int EPI>
__global__ __launch_bounds__(256, 4)
void cheb_gemm(const unsigned short* __restrict__ A,
               const unsigned short* __restrict__ BT,
               const int Ktot, const int Nn, const int kchunk,
               const float* __restrict__ bias,
               const float* __restrict__ resid,
               void* __restrict__ Cout) {
  __shared__ __align__(16) unsigned short Bs[3][3 * 64 * 32];   // 36 KB
  const int t = threadIdx.x, lane = t & 63, wid = t >> 6;
  const int bm = blockIdx.x * 128, bn = blockIdx.y * 64;
  const int kbase = (int)blockIdx.z * kchunk;
  const int nkt = kchunk >> 5;                                  // even for all our shapes
  const int srow = t >> 2;
  const int ssw  = ((t & 3) ^ ((t >> 2) & 3) ^ ((t >> 4) & 3)) * 8;
  const int frow = lane & 15;
  const int rslot = ((lane >> 4) ^ (lane & 3) ^ ((lane >> 2) & 3)) * 8;
  const int arow = bm + wid * 32 + frow;
  const int ak   = (lane >> 4) * 8;
  const size_t pstride = (size_t)Nn * Ktot;
  f32x4 acc[2][4] = {};

  auto stageB = [&](int buf, int kt) {
    const int kk = kbase + (kt << 5);
    char* lb = (char*)&Bs[buf][0] + (wid << 10);
    #pragma unroll
    for (int p = 0; p < 3; ++p)
      async_copy16(lb + p * 4096,
                   &BT[(size_t)p * pstride + (size_t)(bn + srow) * Ktot + kk + ssw]);
  };
  auto loadA = [&](bf16x8 (&dst)[2], int kt) {
    const int kk = kbase + (kt << 5) + ak;
    #pragma unroll
    for (int m = 0; m < 2; ++m)
      dst[m] = *(const bf16x8*)&A[(size_t)(arow + m * 16) * Ktot + kk];
  };

  bf16x8 aA[2], aB[2];
  // prologue: queue = B(0)[3], A(0)[2], B(1)[3]
  stageB(0, 0);
  loadA(aA, 0);
  if (nkt > 1) stageB(1, 1);

  auto body = [&](bf16x8 (&curA)[2], bf16x8 (&nxtA)[2], int kt) {
    // wait B(kt)+A(kt); leave B(kt+1) (3 loads) in flight
    if (kt + 1 < nkt) asm volatile("s_waitcnt vmcnt(3)" ::: "memory");
    else              asm volatile("s_waitcnt vmcnt(0)" ::: "memory");
    __builtin_amdgcn_s_barrier();
    __builtin_amdgcn_sched_barrier(0);
    const unsigned short* bp = &Bs[kt % 3][0];
    // prefetch next A (regs) and B(kt+2) (LDS, buffer freed at kt-1, barrier-protected)
    if (kt + 1 < nkt) loadA(nxtA, kt + 1);
    if (kt + 2 < nkt) stageB((kt + 2) % 3, kt + 2);
    // in-register power expansion (bf16 trunc; rel err ~2^-9) -- overlaps ds_reads
    bf16x8 a2[2], a3[2];
    #pragma unroll
    for (int m = 0; m < 2; ++m) {
      const unsigned int* w = (const unsigned int*)&curA[m];
      unsigned int sq[4], cu[4];
      #pragma unroll
      for (int j = 0; j < 4; ++j) {
        const unsigned int u = w[j];
        const float lo = __builtin_bit_cast(float, u << 16);
        const float hi = __builtin_bit_cast(float, u & 0xffff0000u);
        const float lo2 = lo * lo, hi2 = hi * hi;
        const float lo3 = lo2 * lo, hi3 = hi2 * hi;
        sq[j] = (__builtin_bit_cast(unsigned int, hi2) & 0xffff0000u) |
                (__builtin_bit_cast(unsigned int, lo2) >> 16);
        cu[j] = (__builtin_bit_cast(unsigned int, hi3) & 0xffff0000u) |
                (__builtin_bit_cast(unsigned int, lo3) >> 16);
      }
      a2[m] = *(const bf16x8*)sq;
      a3[m] = *(const bf16x8*)cu;
    }
    #pragma unroll
    for (int p = 0; p < 3; ++p) {
      bf16x8 br[4];
      #pragma unroll
      for (int n = 0; n < 4; ++n)
        br[n] = *(const bf16x8*)&bp[(p * 64 + n * 16 + frow) * 32 + rslot];
      #pragma unroll
      for (int m = 0; m < 2; ++m) {
        const bf16x8 a = (p == 0) ? curA[m] : (p == 1) ? a2[m] : a3[m];
        #pragma unroll
        for (int n = 0; n < 4; ++n)
          acc[m][n] = __builtin_amdgcn_mfma_f32_16x16x32_bf16(a, br[n], acc[m][n], 0, 0, 0);
      }
    }
  };

  for (int kt = 0; kt < nkt; kt += 2) {   // nkt even; static reg-set rotation
    body(aA, aB, kt);
    body(aB, aA, kt + 1);
  }

  #pragma unroll
  for (int m = 0; m < 2; ++m) {
    #pragma unroll
    for (int n = 0; n < 4; ++n) {
      #pragma unroll
      for (int r = 0; r < 4; ++r) {
        const int row = bm + wid * 32 + m * 16 + (lane >> 4) * 4 + r;
        const int col = bn + n * 16 + (lane & 15);
        const float v = acc[m][n][r];
        if (EPI == 0) {
          ((unsigned short*)Cout)[(size_t)row * Nn + col] = f2bf(fast_tanh(v + bias[col]));
        } else {
          if (row < TOK)
            ((float*)Cout)[(size_t)row * Nn + col] = v + bias[col] + resid[(size_t)row * Nn + col];
        }
      }
    }
  }
}

// ---------------- attention: one block per (b,head,qhalf), 4 waves ------------------
__global__ __launch_bounds__(256)
void attn_kernel(const unsigned short* __restrict__ qkv, unsigned short* __restrict__ aout) {
  constexpr int VSTR = 232;   // padded col stride (keys), 464B rows: ~2-way banks, 16B aligned
  __shared__ __align__(16) unsigned short Vlds[64 * VSTR];      // V^T [d][key]
  __shared__ __align__(16) unsigned short Plds[4][16 * VSTR];   // per-wave P [q][key]
  const int bh = blockIdx.x;
  const int by = blockIdx.y;                                    // q-half: qt = wid+4*by, +=8
  const int b = bh / NHEADS, hh = bh - b * NHEADS;
  const int t = threadIdx.x, lane = t & 63, wid = t >> 6;
  const size_t base = (size_t)b * SEQ * H3;
  // stage V^T (zero pad keys >= SEQ)
  const int part = t & 7, key0 = t >> 3;
  for (int it = 0; it < 7; ++it) {
    const int key = key0 + it * 32;
    u32x4 raw = {0, 0, 0, 0};
    if (key < SEQ)
      raw = *(const u32x4*)&qkv[base + (size_t)key * H3 + 2 * CH + hh * HD + part * 8];
    const unsigned short* us = (const unsigned short*)&raw;
    #pragma unroll
    for (int e = 0; e < 8; ++e)
      Vlds[(part * 8 + e) * VSTR + key] = us[e];
  }
  // zero P pad columns [208,224)
  for (int idx = t; idx < 4 * 16 * 16; idx += 256) {
    const int buf = idx >> 8, rr = (idx >> 4) & 15, ccc = idx & 15;
    Plds[buf][rr * VSTR + 208 + ccc] = 0;
  }
  __syncthreads();

  for (int qt = wid + 4 * by; qt < 13; qt += 8) {
    const int qrow = qt * 16 + (lane & 15);              // may be >=SEQ; stores guarded
    const size_t qbase = base + (size_t)qrow * H3 + hh * HD + (lane >> 4) * 8;
    const bf16x8 qf0 = *(const bf16x8*)&qkv[qbase];
    const bf16x8 qf1 = *(const bf16x8*)&qkv[qbase + 32];
    float sv[13][4];
    #pragma unroll
    for (int ktile = 0; ktile < 13; ++ktile) {
      const int keyc = ktile * 16 + (lane & 15);
      const size_t kbase = base + (size_t)keyc * H3 + CH + hh * HD + (lane >> 4) * 8;
      const bf16x8 kf0 = *(const bf16x8*)&qkv[kbase];
      const bf16x8 kf1 = *(const bf16x8*)&qkv[kbase + 32];
      f32x4 s = {0.f, 0.f, 0.f, 0.f};
      s = __builtin_amdgcn_mfma_f32_16x16x32_bf16(qf0, kf0, s, 0, 0, 0);
      s = __builtin_amdgcn_mfma_f32_16x16x32_bf16(qf1, kf1, s, 0, 0, 0);
      const bool valid = keyc < SEQ;
      #pragma unroll
      for (int r = 0; r < 4; ++r)
        sv[ktile][r] = valid ? s[r] * 0.125f : -INFINITY;
    }
    // softmax over keys: rows live across the 16 lanes of each quarter-wave
    float rsum[4];
    #pragma unroll
    for (int r = 0; r < 4; ++r) {
      float mx = -INFINITY;
      #pragma unroll
      for (int kt2 = 0; kt2 < 13; ++kt2) mx = fmaxf(mx, sv[kt2][r]);
      #pragma unroll
      for (int off = 1; off < 16; off <<= 1) mx = fmaxf(mx, __shfl_xor(mx, off));
      float sum = 0.f;
      #pragma unroll
      for (int kt2 = 0; kt2 < 13; ++kt2) {
        const float p = __expf(sv[kt2][r] - mx);
        sv[kt2][r] = p;
        sum += p;
      }
      #pragma unroll
      for (int off = 1; off < 16; off <<= 1) sum += __shfl_xor(sum, off);
      rsum[r] = sum;
    }
    // P -> LDS (transpose lanes->rows for the PV A-operand)
    const int g4 = (lane >> 4) * 4;
    #pragma unroll
    for (int kt2 = 0; kt2 < 13; ++kt2)
      #pragma unroll
      for (int r = 0; r < 4; ++r)
        Plds[wid][(g4 + r) * VSTR + kt2 * 16 + (lane & 15)] = f2bf(sv[kt2][r]);
    asm volatile("s_waitcnt lgkmcnt(0)" ::: "memory");   // same-wave ds_write -> ds_read
    // O = P @ V
    f32x4 oacc[4] = {};
    #pragma unroll
    for (int ks = 0; ks < 7; ++ks) {
      const bf16x8 pf = *(const bf16x8*)&Plds[wid][(lane & 15) * VSTR + ks * 32 + (lane >> 4) * 8];
      #pragma unroll
      for (int n = 0; n < 4; ++n) {
        const bf16x8 vf = *(const bf16x8*)&Vlds[(n * 16 + (lane & 15)) * VSTR + ks * 32 + (lane >> 4) * 8];
        oacc[n] = __builtin_amdgcn_mfma_f32_16x16x32_bf16(pf, vf, oacc[n], 0, 0, 0);
      }
    }
    #pragma unroll
    for (int n = 0; n < 4; ++n)
      #pragma unroll
      for (int r = 0; r < 4; ++r) {
        const int q = qt * 16 + g4 + r;
        if (q < SEQ) {
          const float val = oacc[n][r] / rsum[r];
          aout[(size_t)(b * SEQ + q) * CH + hh * HD + n * 16 + (lane & 15)] = f2bf(val);
        }
      }
  }
}

extern "C" void kernel_launch(void* const* d_in, const int* in_sizes, int n_in,
                              void* d_out, int out_size, void* d_ws, size_t ws_size,
                              hipStream_t stream) {
  const float* x      = (const float*)d_in[0];
  const float* g1     = (const float*)d_in[1];
  const float* b1     = (const float*)d_in[2];
  const float* w_qkv  = (const float*)d_in[3];
  const float* w_proj = (const float*)d_in[4];
  const float* b_proj = (const float*)d_in[5];
  const float* g2     = (const float*)d_in[6];
  const float* b2     = (const float*)d_in[7];
  const float* c1     = (const float*)d_in[8];
  const float* c2     = (const float*)d_in[9];

  // ---- workspace (no aliasing; peak ~171 MB) ----
  char* ws = (char*)d_ws;
  size_t off = 0;
  auto alloc = [&](size_t bytes) { size_t o = off; off += (bytes + 255) & ~(size_t)255; return o; };
  unsigned short* h      = (unsigned short*)(ws + alloc((size_t)TOKP * CH * 2));
  unsigned short* wqkvT  = (unsigned short*)(ws + alloc((size_t)H3 * CH * 2));
  unsigned short* wprojT = (unsigned short*)(ws + alloc((size_t)CH * CH * 2));
  unsigned short* c1T    = (unsigned short*)(ws + alloc((size_t)3 * HID * CH * 2));  // [3][HID][CH]
  unsigned short* c2T    = (unsigned short*)(ws + alloc((size_t)3 * CH * HID * 2));  // [3][CH][HID]
  float* bias1           = (float*)(ws + alloc((size_t)HID * 4));
  float* bias2           = (float*)(ws + alloc((size_t)CH * 4));
  float* part1           = (float*)(ws + alloc((size_t)(CH / 64) * HID * 4));
  float* part2           = (float*)(ws + alloc((size_t)(HID / 64) * CH * 4));
  unsigned short* qkvb   = (unsigned short*)(ws + alloc((size_t)TOKP * H3 * 2));
  unsigned short* aoutb  = (unsigned short*)(ws + alloc((size_t)TOKP * CH * 2));
  float* xmid            = (float*)(ws + alloc((size_t)TOKP * CH * 4));
  unsigned short* tb     = (unsigned short*)(ws + alloc((size_t)TOKP * CH * 2));     // t plane
  unsigned short* ub     = (unsigned short*)(ws + alloc((size_t)TOKP * HID * 2));    // u plane
  (void)ws_size; (void)in_sizes; (void)n_in; (void)out_size;

  // ---- per-launch weight prep (bf16, pre-transposed / cheby-folded) ----
  transpose_bf16<<<dim3(CH / 64, H3 / 64), 256, 0, stream>>>(w_qkv, wqkvT, CH, H3);
  transpose_bf16<<<dim3(CH / 64, CH / 64), 256, 0, stream>>>(w_proj, wprojT, CH, CH);
  cheb_combine<<<dim3(CH / 64, HID / 64), 256, 0, stream>>>(c1, c1T, part1, CH, HID);
  cheb_combine<<<dim3(HID / 64, CH / 64), 256, 0, stream>>>(c2, c2T, part2, HID, CH);
  bias_finish<<<dim3(HID / 256), 256, 0, stream>>>(part1, bias1, CH / 64, HID);
  bias_finish<<<dim3(CH / 256), 256, 0, stream>>>(part2, bias2, HID / 64, CH);
  zero_pad_rows<<<dim3(72), 256, 0, stream>>>(aoutb);

  // ---- main pipeline ----
  ln_kernel<0><<<dim3(TOKP / 4), 256, 0, stream>>>(x, g1, b1, h);
  gemm_kernel<0><<<dim3(TOKP / 128, H3 / 128), 256, 0, stream>>>(h, wqkvT, CH, H3,
                                                                 nullptr, nullptr, qkvb);
  attn_kernel<<<dim3(NBATCH * NHEADS, 2), 256, 0, stream>>>(qkvb, aoutb);
  gemm_kernel<1><<<dim3(TOKP / 128, CH / 128), 256, 0, stream>>>(aoutb, wprojT, CH, CH,
                                                                 b_proj, x, xmid);
  ln_kernel<1><<<dim3(TOKP / 4), 256, 0, stream>>>(xmid, g2, b2, tb);
  // cheby1: fused powers-of-t GEMM, K = 768, 128x64 tiles (50 x 48 blocks)
  cheb_gemm<0><<<dim3(TOKP / 128, HID / 64, 1), 256, 0, stream>>>(tb, c1T, CH, HID, CH,
                                                                  bias1, nullptr, ub);
  // cheby2: fused powers-of-u GEMM, K = 3072, direct fp32 d_out (50 x 12 blocks)
  cheb_gemm<1><<<dim3(TOKP / 128, CH / 64, 1), 256, 0, stream>>>(ub, c2T, HID, CH, HID,
                                                                 bias2, xmid, (float*)d_out);
}

// Round 12
// 425.374 us; speedup vs baseline: 1.0219x; 1.0219x over previous
//
#include <hip/hip_runtime.h>
#include <hip/hip_bf16.h>
#include <cmath>
#include <cstdint>
#include <cstddef>

#define DEV __device__ __forceinline__

typedef __attribute__((ext_vector_type(4))) float f32x4;
typedef __attribute__((ext_vector_type(8))) short bf16x8;
typedef __attribute__((ext_vector_type(4))) unsigned int u32x4;
typedef __attribute__((ext_vector_type(4))) unsigned short u16x4;

constexpr int NBATCH = 32;
constexpr int SEQ    = 197;
constexpr int CH     = 768;
constexpr int H3     = 3 * CH;      // 2304
constexpr int NHEADS = 12;
constexpr int HD     = 64;
constexpr int HID    = 3072;
constexpr int TOK    = NBATCH * SEQ;  // 6304
constexpr int TOKP   = 6400;          // padded to 50*128
constexpr int KSPLIT = 2;             // cheby2 split-K factor
constexpr float LNEPS = 1e-5f;

DEV unsigned short f2bf(float f) {
  unsigned int u = __builtin_bit_cast(unsigned int, f);
  u += 0x7fffu + ((u >> 16) & 1u);   // RNE
  return (unsigned short)(u >> 16);
}
DEV float bf2f(unsigned short s) {
  unsigned int u = ((unsigned int)s) << 16;
  return __builtin_bit_cast(float, u);
}

// fast tanh: tanh(x) = 1 - 2/(e^{2x}+1); saturates correctly at +-1
DEV float fast_tanh(float x) {
  const float e = __expf(2.f * x);
  return 1.f - 2.f * __builtin_amdgcn_rcpf(e + 1.f);
}

// async global->LDS, 16B per lane; lds dest is wave-uniform base + lane*16 (linear)
DEV void async_copy16(void* lds, const void* gmem) {
  __builtin_amdgcn_global_load_lds(
      (const __attribute__((address_space(1))) unsigned int*)gmem,
      (__attribute__((address_space(3))) unsigned int*)lds, 16, 0, 0);
}

// ---------------- LayerNorm (one wave per row), optional tanh, bf16 out -------------
template <int DO_TANH>
__global__ void ln_kernel(const float* __restrict__ xin, const float* __restrict__ gg,
                          const float* __restrict__ bb, unsigned short* __restrict__ outp) {
  const int row  = blockIdx.x * 4 + (threadIdx.x >> 6);
  const int lane = threadIdx.x & 63;
  if (row >= TOK) {           // pad rows -> zeros (row < TOKP by grid)
    u16x4 z = {0, 0, 0, 0};
    #pragma unroll
    for (int c = 0; c < 3; ++c)
      *(u16x4*)&outp[(size_t)row * CH + c * 256 + lane * 4] = z;
    return;
  }
  f32x4 v[3];
  float s = 0.f, s2 = 0.f;
  #pragma unroll
  for (int c = 0; c < 3; ++c) {
    v[c] = *(const f32x4*)&xin[(size_t)row * CH + c * 256 + lane * 4];
    #pragma unroll
    for (int e = 0; e < 4; ++e) { s += v[c][e]; s2 += v[c][e] * v[c][e]; }
  }
  #pragma unroll
  for (int off = 32; off; off >>= 1) { s += __shfl_xor(s, off); s2 += __shfl_xor(s2, off); }
  const float mean = s * (1.f / CH);
  const float var  = s2 * (1.f / CH) - mean * mean;
  const float rs   = rsqrtf(var + LNEPS);
  #pragma unroll
  for (int c = 0; c < 3; ++c) {
    f32x4 gv = *(const f32x4*)&gg[c * 256 + lane * 4];
    f32x4 bv = *(const f32x4*)&bb[c * 256 + lane * 4];
    u16x4 o;
    #pragma unroll
    for (int e = 0; e < 4; ++e) {
      float f = (v[c][e] - mean) * rs * gv[e] + bv[e];
      if (DO_TANH) f = fast_tanh(f);
      o[e] = f2bf(f);
    }
    *(u16x4*)&outp[(size_t)row * CH + c * 256 + lane * 4] = o;
  }
}

// ---------------- transpose fp32 (K x N) -> bf16 (N x K) ----------------------------
__global__ void transpose_bf16(const float* __restrict__ in, unsigned short* __restrict__ outp,
                               int K, int N) {
  __shared__ unsigned short tile[64][65];
  const int k0 = blockIdx.x * 64, n0 = blockIdx.y * 64;
  const int tc = threadIdx.x & 63, tr = threadIdx.x >> 6;
  #pragma unroll
  for (int rr = 0; rr < 64; rr += 4)
    tile[rr + tr][tc] = f2bf(in[(size_t)(k0 + rr + tr) * N + n0 + tc]);
  __syncthreads();
  #pragma unroll
  for (int rr = 0; rr < 64; rr += 4)
    outp[(size_t)(n0 + rr + tr) * K + k0 + tc] = tile[tc][rr + tr];
}

// -------- fold cheby coeffs (I,O,4) -> monomial weight planes bf16 [3][O][I] --------
// W1 = c[...,1]-3c[...,3], W2 = 2c[...,2], W3 = 4c[...,3]
// Also emits per-(i-block) partial bias rows: partial[iblk][o] = sum_{i in blk}(c0 - c2)
__global__ void cheb_combine(const float* __restrict__ cc, unsigned short* __restrict__ outp,
                             float* __restrict__ partial, int I, int O) {
  __shared__ unsigned short t1[64][65];
  __shared__ unsigned short t2[64][65];
  __shared__ unsigned short t3[64][65];
  __shared__ float psum[4][64];
  const int i0 = blockIdx.x * 64, o0 = blockIdx.y * 64;
  const int tc = threadIdx.x & 63, tr = threadIdx.x >> 6;
  float bs = 0.f;
  #pragma unroll
  for (int rr = 0; rr < 64; rr += 4) {
    f32x4 v = *(const f32x4*)&cc[((size_t)(i0 + rr + tr) * O + (o0 + tc)) * 4];
    t1[rr + tr][tc] = f2bf(v[1] - 3.f * v[3]);
    t2[rr + tr][tc] = f2bf(2.f * v[2]);
    t3[rr + tr][tc] = f2bf(4.f * v[3]);
    bs += v[0] - v[2];
  }
  psum[tr][tc] = bs;
  __syncthreads();
  const size_t plane = (size_t)O * I;
  #pragma unroll
  for (int rr = 0; rr < 64; rr += 4) {
    size_t ob = (size_t)(o0 + rr + tr) * I + i0 + tc;
    outp[ob]             = t1[tc][rr + tr];
    outp[ob + plane]     = t2[tc][rr + tr];
    outp[ob + 2 * plane] = t3[tc][rr + tr];
  }
  if (tr == 0)
    partial[(size_t)blockIdx.x * O + o0 + tc] =
        psum[0][tc] + psum[1][tc] + psum[2][tc] + psum[3][tc];
}

// deterministic finish: bias[o] = sum_k partial[k][o]
__global__ void bias_finish(const float* __restrict__ partial, float* __restrict__ bias,
                            int nblk, int O) {
  const int o = blockIdx.x * 256 + threadIdx.x;
  float s = 0.f;
  for (int k = 0; k < nblk; ++k) s += partial[(size_t)k * O + o];
  bias[o] = s;
}

__global__ void zero_pad_rows(unsigned short* __restrict__ p) {
  const size_t idx = ((size_t)blockIdx.x * 256 + threadIdx.x) * 4;
  u16x4 z = {0, 0, 0, 0};
  *(u16x4*)&p[(size_t)TOK * CH + idx] = z;
}

// ---------------- 128x128x32 bf16 MFMA GEMM, 1-ahead prefetch (round-6 form) --------
// A bf16 [TOKP][Ktot] row-major; BT bf16 [Nn][Ktot]. 256 thr, 2x2 waves.
// EPI: 0 -> bf16 C[row][Nn] ; 1 -> fp32 acc+bias+resid (0 on pad rows)
template <int EPI>
__global__ __launch_bounds__(256)
void gemm_kernel(const unsigned short* __restrict__ A,
                 const unsigned short* __restrict__ BT,
                 const int Ktot, const int Nn,
                 const float* __restrict__ bias,
                 const float* __restrict__ resid,
                 void* __restrict__ Cout) {
  __shared__ __align__(16) unsigned short As[2][128 * 32];
  __shared__ __align__(16) unsigned short Bs[2][128 * 32];
  const int t = threadIdx.x;
  const int lane = t & 63;
  const int wid = t >> 6;
  const int wm = wid >> 1, wn = wid & 1;
  const int bm = blockIdx.x * 128;
  const int bn = blockIdx.y * 128;
  const int srow = t >> 2;          // staging row within 64-row half
  const int scol = (t & 3) * 8;     // staging col (bf16)
  const int nkt = Ktot >> 5;
  f32x4 acc[4][4] = {};

  auto stage = [&](int buf, int kt) {
    const int kk = kt << 5;
    char* lb = (char*)&Bs[buf][0] + (wid << 10);
    async_copy16(lb,        &BT[(size_t)(bn + srow) * Ktot + kk + scol]);
    async_copy16(lb + 4096, &BT[(size_t)(bn + 64 + srow) * Ktot + kk + scol]);
    char* la = (char*)&As[buf][0] + (wid << 10);
    async_copy16(la,        &A[(size_t)(bm + srow) * Ktot + kk + scol]);
    async_copy16(la + 4096, &A[(size_t)(bm + 64 + srow) * Ktot + kk + scol]);
  };

  int cur = 0;
  stage(0, 0);
  for (int kt = 0; kt < nkt; ++kt) {
    if (kt + 1 < nkt) {
      stage(cur ^ 1, kt + 1);                       // issue next tile's loads first
      asm volatile("s_waitcnt vmcnt(4)" ::: "memory");   // cur tile's 4 loads done
    } else {
      asm volatile("s_waitcnt vmcnt(0)" ::: "memory");
    }
    __builtin_amdgcn_s_barrier();                   // cur staged by all waves
    __builtin_amdgcn_sched_barrier(0);
    bf16x8 af[4], bfr[4];
    const int frow = lane & 15;
    const int fk = (lane >> 4) * 8;
    #pragma unroll
    for (int m = 0; m < 4; ++m)
      af[m] = *(const bf16x8*)&As[cur][(wm * 64 + m * 16 + frow) * 32 + fk];
    #pragma unroll
    for (int n = 0; n < 4; ++n)
      bfr[n] = *(const bf16x8*)&Bs[cur][(wn * 64 + n * 16 + frow) * 32 + fk];
    #pragma unroll
    for (int m = 0; m < 4; ++m)
      #pragma unroll
      for (int n = 0; n < 4; ++n)
        acc[m][n] = __builtin_amdgcn_mfma_f32_16x16x32_bf16(af[m], bfr[n], acc[m][n], 0, 0, 0);
    __builtin_amdgcn_s_barrier();                   // reads done before next overwrite
    cur ^= 1;
  }
  // epilogue: C/D frag layout col=lane&15, row=4*(lane>>4)+r  [verified m89]
  #pragma unroll
  for (int m = 0; m < 4; ++m) {
    #pragma unroll
    for (int n = 0; n < 4; ++n) {
      #pragma unroll
      for (int r = 0; r < 4; ++r) {
        const int row = bm + wm * 64 + m * 16 + (lane >> 4) * 4 + r;
        const int col = bn + wn * 64 + n * 16 + (lane & 15);
        const float v = acc[m][n][r];
        if (EPI == 0) {
          ((unsigned short*)Cout)[(size_t)row * Nn + col] = f2bf(v);
        } else {
          float o = 0.f;
          if (row < TOK) o = v + bias[col] + resid[(size_t)row * Nn + col];
          ((float*)Cout)[(size_t)row * Nn + col] = o;
        }
      }
    }
  }
}

// ---------------- fused ChebyKAN GEMM (round-7 form + v_perm pack) ------------------
// 128x64 tile, 4x1 waves. A global->reg direct (1-ahead, 2 named reg sets); powers
// expanded in regs with v_perm_b32 packing (1 op vs and/lshr/or).
// B: 3 power planes [3][Nn][Ktot]; LDS 3-buffer, 2-deep prefetch, ONE barrier/k-tile,
// counted vmcnt(3). T2 swizzle on Bs. 36 KB LDS, ~64 VGPR.
// EPI: 0 -> bf16 fast_tanh(acc+bias) -> C[row][Nn]
//      1 -> fp32 partial -> C[(z*TOKP+row)][Nn]   (split-K over blockIdx.z)
template <int EPI>
__global__ __launch_bounds__(256, 4)
void cheb_gemm(const unsigned short* __restrict__ A,
               const unsigned short* __restrict__ BT,
               const int Ktot, const int Nn, const int kchunk,
               const float* __restrict__ bias,
               void* __restrict__ Cout) {
  __shared__ __align__(16) unsigned short Bs[3][3 * 64 * 32];   // 36 KB
  const int t = threadIdx.x, lane = t & 63, wid = t >> 6;
  const int bm = blockIdx.x * 128, bn = blockIdx.y * 64;
  const int kbase = (int)blockIdx.z * kchunk;
  const int nkt = kchunk >> 5;                                  // even for all our shapes
  const int srow = t >> 2;
  const int ssw  = ((t & 3) ^ ((t >> 2) & 3) ^ ((t >> 4) & 3)) * 8;
  const int frow = lane & 15;
  const int rslot = ((lane >> 4) ^ (lane & 3) ^ ((lane >> 2) & 3)) * 8;
  const int arow = bm + wid * 32 + frow;
  const int ak   = (lane >> 4) * 8;
  const size_t pstride = (size_t)Nn * Ktot;
  f32x4 acc[2][4] = {};

  auto stageB = [&](int buf, int kt) {
    const int kk = kbase + (kt << 5);
    char* lb = (char*)&Bs[buf][0] + (wid << 10);
    #pragma unroll
    for (int p = 0; p < 3; ++p)
      async_copy16(lb + p * 4096,
                   &BT[(size_t)p * pstride + (size_t)(bn + srow) * Ktot + kk + ssw]);
  };
  auto loadA = [&](bf16x8 (&dst)[2], int kt) {
    const int kk = kbase + (kt << 5) + ak;
    #pragma unroll
    for (int m = 0; m < 2; ++m)
      dst[m] = *(const bf16x8*)&A[(size_t)(arow + m * 16) * Ktot + kk];
  };

  bf16x8 aA[2], aB[2];
  // prologue: queue = B(0)[3], A(0)[2], B(1)[3]
  stageB(0, 0);
  loadA(aA, 0);
  if (nkt > 1) stageB(1, 1);

  auto body = [&](bf16x8 (&curA)[2], bf16x8 (&nxtA)[2], int kt) {
    // wait B(kt)+A(kt); leave B(kt+1) (3 loads) in flight
    if (kt + 1 < nkt) asm volatile("s_waitcnt vmcnt(3)" ::: "memory");
    else              asm volatile("s_waitcnt vmcnt(0)" ::: "memory");
    __builtin_amdgcn_s_barrier();
    __builtin_amdgcn_sched_barrier(0);
    const unsigned short* bp = &Bs[kt % 3][0];
    // prefetch next A (regs) and B(kt+2) (LDS, buffer freed at kt-1, barrier-protected)
    if (kt + 1 < nkt) loadA(nxtA, kt + 1);
    if (kt + 2 < nkt) stageB((kt + 2) % 3, kt + 2);
    // in-register power expansion; v_perm_b32 packs the two f32 high-halves in 1 op
    bf16x8 a2[2], a3[2];
    #pragma unroll
    for (int m = 0; m < 2; ++m) {
      const unsigned int* w = (const unsigned int*)&curA[m];
      unsigned int sq[4], cu[4];
      #pragma unroll
      for (int j = 0; j < 4; ++j) {
        const unsigned int u = w[j];
        const float lo = __builtin_bit_cast(float, u << 16);
        const float hi = __builtin_bit_cast(float, u & 0xffff0000u);
        const float lo2 = lo * lo, hi2 = hi * hi;
        const float lo3 = lo2 * lo, hi3 = hi2 * hi;
        sq[j] = __builtin_amdgcn_perm(__builtin_bit_cast(unsigned int, hi2),
                                      __builtin_bit_cast(unsigned int, lo2), 0x07060302u);
        cu[j] = __builtin_amdgcn_perm(__builtin_bit_cast(unsigned int, hi3),
                                      __builtin_bit_cast(unsigned int, lo3), 0x07060302u);
      }
      a2[m] = *(const bf16x8*)sq;
      a3[m] = *(const bf16x8*)cu;
    }
    #pragma unroll
    for (int p = 0; p < 3; ++p) {
      bf16x8 br[4];
      #pragma unroll
      for (int n = 0; n < 4; ++n)
        br[n] = *(const bf16x8*)&bp[(p * 64 + n * 16 + frow) * 32 + rslot];
      #pragma unroll
      for (int m = 0; m < 2; ++m) {
        const bf16x8 a = (p == 0) ? curA[m] : (p == 1) ? a2[m] : a3[m];
        #pragma unroll
        for (int n = 0; n < 4; ++n)
          acc[m][n] = __builtin_amdgcn_mfma_f32_16x16x32_bf16(a, br[n], acc[m][n], 0, 0, 0);
      }
    }
  };

  for (int kt = 0; kt < nkt; kt += 2) {   // nkt even; static reg-set rotation
    body(aA, aB, kt);
    body(aB, aA, kt + 1);
  }

  #pragma unroll
  for (int m = 0; m < 2; ++m) {
    #pragma unroll
    for (int n = 0; n < 4; ++n) {
      #pragma unroll
      for (int r = 0; r < 4; ++r) {
        const int row = bm + wid * 32 + m * 16 + (lane >> 4) * 4 + r;
        const int col = bn + n * 16 + (lane & 15);
        const float v = acc[m][n][r];
        if (EPI == 0) {
          ((unsigned short*)Cout)[(size_t)row * Nn + col] = f2bf(fast_tanh(v + bias[col]));
        } else {
          ((float*)Cout)[((size_t)blockIdx.z * TOKP + row) * Nn + col] = v;
        }
      }
    }
  }
}

// split-K finish for cheby2: out = sum_z part + bias + resid (rows < TOK)
__global__ void cheb2_reduce(const float* __restrict__ part, const float* __restrict__ bias,
                             const float* __restrict__ resid, float* __restrict__ outp) {
  const size_t idx = ((size_t)blockIdx.x * 256 + threadIdx.x) * 4;
  const int col = (int)(idx % CH);
  f32x4 s = *(const f32x4*)&part[idx];
  #pragma unroll
  for (int z = 1; z < KSPLIT; ++z) {
    f32x4 p = *(const f32x4*)&part[(size_t)z * TOKP * CH + idx];
    #pragma unroll
    for (int e = 0; e < 4; ++e) s[e] += p[e];
  }
  const f32x4 bv = *(const f32x4*)&bias[col];
  const f32x4 rv = *(const f32x4*)&resid[idx];
  f32x4 o;
  #pragma unroll
  for (int e = 0; e < 4; ++e) o[e] = s[e] + bv[e] + rv[e];
  *(f32x4*)&outp[idx] = o;
}

// ---------------- attention: one block per (b,head,qhalf), 4 waves ------------------
__global__ __launch_bounds__(256)
void attn_kernel(const unsigned short* __restrict__ qkv, unsigned short* __restrict__ aout) {
  constexpr int VSTR = 232;   // padded col stride (keys), 464B rows: ~2-way banks, 16B aligned
  __shared__ __align__(16) unsigned short Vlds[64 * VSTR];      // V^T [d][key]
  __shared__ __align__(16) unsigned short Plds[4][16 * VSTR];   // per-wave P [q][key]
  const int bh = blockIdx.x;
  const int by = blockIdx.y;                                    // q-half: qt = wid+4*by, +=8
  const int b = bh / NHEADS, hh = bh - b * NHEADS;
  const int t = threadIdx.x, lane = t & 63, wid = t >> 6;
  const size_t base = (size_t)b * SEQ * H3;
  // stage V^T (zero pad keys >= SEQ)
  const int part = t & 7, key0 = t >> 3;
  for (int it = 0; it < 7; ++it) {
    const int key = key0 + it * 32;
    u32x4 raw = {0, 0, 0, 0};
    if (key < SEQ)
      raw = *(const u32x4*)&qkv[base + (size_t)key * H3 + 2 * CH + hh * HD + part * 8];
    const unsigned short* us = (const unsigned short*)&raw;
    #pragma unroll
    for (int e = 0; e < 8; ++e)
      Vlds[(part * 8 + e) * VSTR + key] = us[e];
  }
  // zero P pad columns [208,224)
  for (int idx = t; idx < 4 * 16 * 16; idx += 256) {
    const int buf = idx >> 8, rr = (idx >> 4) & 15, ccc = idx & 15;
    Plds[buf][rr * VSTR + 208 + ccc] = 0;
  }
  __syncthreads();

  for (int qt = wid + 4 * by; qt < 13; qt += 8) {
    const int qrow = qt * 16 + (lane & 15);              // may be >=SEQ; stores guarded
    const size_t qbase = base + (size_t)qrow * H3 + hh * HD + (lane >> 4) * 8;
    const bf16x8 qf0 = *(const bf16x8*)&qkv[qbase];
    const bf16x8 qf1 = *(const bf16x8*)&qkv[qbase + 32];
    float sv[13][4];
    #pragma unroll
    for (int ktile = 0; ktile < 13; ++ktile) {
      const int keyc = ktile * 16 + (lane & 15);
      const size_t kbase = base + (size_t)keyc * H3 + CH + hh * HD + (lane >> 4) * 8;
      const bf16x8 kf0 = *(const bf16x8*)&qkv[kbase];
      const bf16x8 kf1 = *(const bf16x8*)&qkv[kbase + 32];
      f32x4 s = {0.f, 0.f, 0.f, 0.f};
      s = __builtin_amdgcn_mfma_f32_16x16x32_bf16(qf0, kf0, s, 0, 0, 0);
      s = __builtin_amdgcn_mfma_f32_16x16x32_bf16(qf1, kf1, s, 0, 0, 0);
      const bool valid = keyc < SEQ;
      #pragma unroll
      for (int r = 0; r < 4; ++r)
        sv[ktile][r] = valid ? s[r] * 0.125f : -INFINITY;
    }
    // softmax over keys: rows live across the 16 lanes of each quarter-wave
    float rsum[4];
    #pragma unroll
    for (int r = 0; r < 4; ++r) {
      float mx = -INFINITY;
      #pragma unroll
      for (int kt2 = 0; kt2 < 13; ++kt2) mx = fmaxf(mx, sv[kt2][r]);
      #pragma unroll
      for (int off = 1; off < 16; off <<= 1) mx = fmaxf(mx, __shfl_xor(mx, off));
      float sum = 0.f;
      #pragma unroll
      for (int kt2 = 0; kt2 < 13; ++kt2) {
        const float p = __expf(sv[kt2][r] - mx);
        sv[kt2][r] = p;
        sum += p;
      }
      #pragma unroll
      for (int off = 1; off < 16; off <<= 1) sum += __shfl_xor(sum, off);
      rsum[r] = sum;
    }
    // P -> LDS (transpose lanes->rows for the PV A-operand)
    const int g4 = (lane >> 4) * 4;
    #pragma unroll
    for (int kt2 = 0; kt2 < 13; ++kt2)
      #pragma unroll
      for (int r = 0; r < 4; ++r)
        Plds[wid][(g4 + r) * VSTR + kt2 * 16 + (lane & 15)] = f2bf(sv[kt2][r]);
    asm volatile("s_waitcnt lgkmcnt(0)" ::: "memory");   // same-wave ds_write -> ds_read
    // O = P @ V
    f32x4 oacc[4] = {};
    #pragma unroll
    for (int ks = 0; ks < 7; ++ks) {
      const bf16x8 pf = *(const bf16x8*)&Plds[wid][(lane & 15) * VSTR + ks * 32 + (lane >> 4) * 8];
      #pragma unroll
      for (int n = 0; n < 4; ++n) {
        const bf16x8 vf = *(const bf16x8*)&Vlds[(n * 16 + (lane & 15)) * VSTR + ks * 32 + (lane >> 4) * 8];
        oacc[n] = __builtin_amdgcn_mfma_f32_16x16x32_bf16(pf, vf, oacc[n], 0, 0, 0);
      }
    }
    #pragma unroll
    for (int n = 0; n < 4; ++n)
      #pragma unroll
      for (int r = 0; r < 4; ++r) {
        const int q = qt * 16 + g4 + r;
        if (q < SEQ) {
          const float val = oacc[n][r] / rsum[r];
          aout[(size_t)(b * SEQ + q) * CH + hh * HD + n * 16 + (lane & 15)] = f2bf(val);
        }
      }
  }
}

extern "C" void kernel_launch(void* const* d_in, const int* in_sizes, int n_in,
                              void* d_out, int out_size, void* d_ws, size_t ws_size,
                              hipStream_t stream) {
  const float* x      = (const float*)d_in[0];
  const float* g1     = (const float*)d_in[1];
  const float* b1     = (const float*)d_in[2];
  const float* w_qkv  = (const float*)d_in[3];
  const float* w_proj = (const float*)d_in[4];
  const float* b_proj = (const float*)d_in[5];
  const float* g2     = (const float*)d_in[6];
  const float* b2     = (const float*)d_in[7];
  const float* c1     = (const float*)d_in[8];
  const float* c2     = (const float*)d_in[9];

  // ---- workspace (no aliasing; peak ~210 MB) ----
  char* ws = (char*)d_ws;
  size_t off = 0;
  auto alloc = [&](size_t bytes) { size_t o = off; off += (bytes + 255) & ~(size_t)255; return o; };
  unsigned short* h      = (unsigned short*)(ws + alloc((size_t)TOKP * CH * 2));
  unsigned short* wqkvT  = (unsigned short*)(ws + alloc((size_t)H3 * CH * 2));
  unsigned short* wprojT = (unsigned short*)(ws + alloc((size_t)CH * CH * 2));
  unsigned short* c1T    = (unsigned short*)(ws + alloc((size_t)3 * HID * CH * 2));  // [3][HID][CH]
  unsigned short* c2T    = (unsigned short*)(ws + alloc((size_t)3 * CH * HID * 2));  // [3][CH][HID]
  float* bias1           = (float*)(ws + alloc((size_t)HID * 4));
  float* bias2           = (float*)(ws + alloc((size_t)CH * 4));
  float* part1           = (float*)(ws + alloc((size_t)(CH / 64) * HID * 4));
  float* part2           = (float*)(ws + alloc((size_t)(HID / 64) * CH * 4));
  unsigned short* qkvb   = (unsigned short*)(ws + alloc((size_t)TOKP * H3 * 2));
  unsigned short* aoutb  = (unsigned short*)(ws + alloc((size_t)TOKP * CH * 2));
  float* xmid            = (float*)(ws + alloc((size_t)TOKP * CH * 4));
  unsigned short* tb     = (unsigned short*)(ws + alloc((size_t)TOKP * CH * 2));     // t plane
  unsigned short* ub     = (unsigned short*)(ws + alloc((size_t)TOKP * HID * 2));    // u plane
  float* partK           = (float*)(ws + alloc((size_t)KSPLIT * TOKP * CH * 4));
  (void)ws_size; (void)in_sizes; (void)n_in; (void)out_size;

  // ---- per-launch weight prep (bf16, pre-transposed / cheby-folded) ----
  transpose_bf16<<<dim3(CH / 64, H3 / 64), 256, 0, stream>>>(w_qkv, wqkvT, CH, H3);
  transpose_bf16<<<dim3(CH / 64, CH / 64), 256, 0, stream>>>(w_proj, wprojT, CH, CH);
  cheb_combine<<<dim3(CH / 64, HID / 64), 256, 0, stream>>>(c1, c1T, part1, CH, HID);
  cheb_combine<<<dim3(HID / 64, CH / 64), 256, 0, stream>>>(c2, c2T, part2, HID, CH);
  bias_finish<<<dim3(HID / 256), 256, 0, stream>>>(part1, bias1, CH / 64, HID);
  bias_finish<<<dim3(CH / 256), 256, 0, stream>>>(part2, bias2, HID / 64, CH);
  zero_pad_rows<<<dim3(72), 256, 0, stream>>>(aoutb);

  // ---- main pipeline ----
  ln_kernel<0><<<dim3(TOKP / 4), 256, 0, stream>>>(x, g1, b1, h);
  gemm_kernel<0><<<dim3(TOKP / 128, H3 / 128), 256, 0, stream>>>(h, wqkvT, CH, H3,
                                                                 nullptr, nullptr, qkvb);
  attn_kernel<<<dim3(NBATCH * NHEADS, 2), 256, 0, stream>>>(qkvb, aoutb);
  gemm_kernel<1><<<dim3(TOKP / 128, CH / 128), 256, 0, stream>>>(aoutb, wprojT, CH, CH,
                                                                 b_proj, x, xmid);
  ln_kernel<1><<<dim3(TOKP / 4), 256, 0, stream>>>(xmid, g2, b2, tb);
  // cheby1: fused powers-of-t GEMM, K = 768, 128x64 tiles (50 x 48 blocks)
  cheb_gemm<0><<<dim3(TOKP / 128, HID / 64, 1), 256, 0, stream>>>(tb, c1T, CH, HID, CH,
                                                                  bias1, ub);
  // cheby2: fused powers-of-u GEMM, K = 3072, split-K x2 (50 x 12 x 2 blocks)
  cheb_gemm<1><<<dim3(TOKP / 128, CH / 64, KSPLIT), 256, 0, stream>>>(ub, c2T, HID, CH,
                                                                      HID / KSPLIT,
                                                                      nullptr, partK);
  cheb2_reduce<<<dim3(TOK * CH / 1024), 256, 0, stream>>>(partK, bias2, xmid, (float*)d_out);
}